// Round 7
// baseline (112.772 us; speedup 1.0000x reference)
//
#include <hip/hip_runtime.h>
#include <hip/hip_bf16.h>

// LiftedStructureLoss on MI355X (gfx950)
// N=8192, D=128 fp32 embeddings; int labels (0..99); scalar fp32 out.
//
// Structure:
//   prep:     sq[] + bf16 convert (fat blocks)
//   bucket:   single-block zero+hist+scan+scatter (labels -> idxbuf); zeroes ticket
//   pass1:    persistent upper-triangle 128x128 tiles (2 tiles/block),
//             row+col sums of exp(-d) over negatives -> partial1
//   reduce1:  partial1 -> sum_exp[N]  (x e, folding the MARGIN=1 exp)
//   pass2:    per-label blocks, within-label Gram (~1% of pairs), loss+n_pos;
//             last block (ticket) reduces partials -> out
//
// Exactness: e * sum(exp(-d)) == sum(exp(1-d)) up to fp rounding; scalar
// output tolerance is 1.245, bf16-Gram noise ~1e-2.

typedef __attribute__((ext_vector_type(8))) short bf16x8;
typedef __attribute__((ext_vector_type(4))) float f32x4;

__device__ __forceinline__ unsigned short f2bf(float f) {
    unsigned u = __float_as_uint(f);
    u += 0x7fffu + ((u >> 16) & 1u);   // round-to-nearest-even
    return (unsigned short)(u >> 16);
}

// 256 blocks x 256 thr; each wave handles 8 rows.
__global__ __launch_bounds__(256) void prep_kernel(
    const float* __restrict__ e, float* __restrict__ sq,
    unsigned* __restrict__ ebf, int N) {
    const int lane = threadIdx.x & 63, wid = threadIdx.x >> 6;
    const int rowbase = (blockIdx.x * 4 + wid) * 8;
    #pragma unroll
    for (int it = 0; it < 8; ++it) {
        int row = rowbase + it;
        if (row >= N) break;
        float2 v = ((const float2*)(e + (size_t)row * 128))[lane];
        float s = v.x * v.x + v.y * v.y;
        #pragma unroll
        for (int off = 1; off < 64; off <<= 1) s += __shfl_xor(s, off, 64);
        if (lane == 0) sq[row] = s;
        unsigned bits = (unsigned)f2bf(v.x) | ((unsigned)f2bf(v.y) << 16);
        ebf[(size_t)row * 64 + lane] = bits;
    }
}

// Single block: zero + histogram + exclusive scan + scatter; zeroes ticket.
__global__ __launch_bounds__(1024) void bucket_kernel(
    const int* __restrict__ labels,
    int* __restrict__ counts_out,    // [256]
    int* __restrict__ offsets_out,   // [256]
    int* __restrict__ idxbuf,        // [N]
    unsigned* __restrict__ ticket,
    int N)
{
    __shared__ int cnt[256];
    __shared__ int off[256];
    const int tid = threadIdx.x;
    if (tid == 0) *ticket = 0u;
    if (tid < 256) cnt[tid] = 0;
    __syncthreads();
    for (int i = tid; i < N; i += 1024)
        atomicAdd(&cnt[(unsigned)labels[i] & 255u], 1);
    __syncthreads();
    if (tid < 64) {
        int base = tid * 4;
        int c0 = cnt[base], c1 = cnt[base + 1], c2 = cnt[base + 2], c3 = cnt[base + 3];
        int s = c0 + c1 + c2 + c3;
        int v = s;
        #pragma unroll
        for (int d = 1; d < 64; d <<= 1) {
            int u = __shfl_up(v, d, 64);
            if (tid >= d) v += u;
        }
        int excl = v - s;
        off[base]     = excl;
        off[base + 1] = excl + c0;
        off[base + 2] = excl + c0 + c1;
        off[base + 3] = excl + c0 + c1 + c2;
    }
    __syncthreads();
    if (tid < 256) cnt[tid] = off[tid];   // reuse cnt as cursor
    __syncthreads();
    for (int i = tid; i < N; i += 1024) {
        int l = (unsigned)labels[i] & 255u;
        int p = atomicAdd(&cnt[l], 1);
        idxbuf[p] = i;
    }
    __syncthreads();
    if (tid < 256) {
        offsets_out[tid] = off[tid];
        counts_out[tid] = cnt[tid] - off[tid];
    }
}

// PASS 1: persistent blocks, each processes 2 upper-triangle tiles.
// 512 threads (8 waves of 64x32 output). Async global_load_lds staging.
__global__ __launch_bounds__(512) void pass1_kernel(
    const unsigned short* __restrict__ ebf,
    const float* __restrict__ sq,
    const int* __restrict__ labels,
    float* __restrict__ partial1,      // [nCb][N]
    int N, int nCb, int nT)
{
    __shared__ __align__(16) char a_tile[128 * 128];  // one K-chunk (64 cols)
    __shared__ __align__(16) char b_tile[128 * 128];
    __shared__ float rowsum[128];
    __shared__ float colsum[128];

    const int tid = threadIdx.x;
    const int lane = tid & 63, wid = tid >> 6;
    const int wm = (wid >> 2) * 64, wn = (wid & 3) * 32;
    const int lhi = lane >> 4, llo = lane & 15;
    const char* ebfB = (const char*)ebf;

    for (int t = blockIdx.x; t < nT; t += gridDim.x) {
        // decode linear tile id -> (bi, bj), bi <= bj
        int bi = (int)((2.f * nCb + 1.f - __builtin_amdgcn_sqrtf(
                       (2.f * nCb + 1.f) * (2.f * nCb + 1.f) - 8.f * t)) * 0.5f);
        if (bi < 0) bi = 0;
        if (bi > nCb - 1) bi = nCb - 1;
        while (bi + 1 <= nCb - 1 && (bi + 1) * (2 * nCb - bi) / 2 <= t) ++bi;
        while (bi > 0 && bi * (2 * nCb - bi + 1) / 2 > t) --bi;
        const int bj = bi + (t - bi * (2 * nCb - bi + 1) / 2);
        const bool diag = (bi == bj);
        const int brow = bi * 128, bcol = bj * 128;

        if (tid < 128) { rowsum[tid] = 0.f; colsum[tid] = 0.f; }

        f32x4 acc[4][2];
        #pragma unroll
        for (int m = 0; m < 4; ++m)
            #pragma unroll
            for (int n = 0; n < 2; ++n)
                acc[m][n] = (f32x4){0.f, 0.f, 0.f, 0.f};

        #pragma unroll
        for (int c = 0; c < 2; ++c) {
            // async stage: 2048 16B slots, wave wid covers [wid*256, +256)
            #pragma unroll
            for (int k = 0; k < 4; ++k) {
                int s = wid * 256 + k * 64;          // wave-uniform slot base
                int tsel = s >> 10;                  // 0: a_tile, 1: b_tile
                int ls = s & 1023;
                int sl = ls + lane;                  // per-lane slot within tile
                int r = sl >> 3, j = sl & 7;
                int grow = (tsel ? bcol : brow) + r;
                const void* g = ebfB + ((size_t)grow << 8) + c * 128 + ((j ^ (r & 7)) << 4);
                char* l = (tsel ? b_tile : a_tile) + ls * 16;   // wave-uniform
                __builtin_amdgcn_global_load_lds(
                    (const __attribute__((address_space(1))) unsigned*)g,
                    (__attribute__((address_space(3))) unsigned*)l, 16, 0, 0);
            }
            __syncthreads();   // drains vmcnt before ds_read

            #pragma unroll
            for (int h = 0; h < 2; ++h) {
                const int cb = h * 64 + lhi * 16;
                bf16x8 af[4], bfr[2];
                #pragma unroll
                for (int m = 0; m < 4; ++m) {
                    int r = wm + m * 16 + llo;
                    af[m] = *(const bf16x8*)(a_tile + r * 128 + (cb ^ ((r & 7) << 4)));
                }
                #pragma unroll
                for (int n = 0; n < 2; ++n) {
                    int r = wn + n * 16 + llo;
                    bfr[n] = *(const bf16x8*)(b_tile + r * 128 + (cb ^ ((r & 7) << 4)));
                }
                #pragma unroll
                for (int m = 0; m < 4; ++m)
                    #pragma unroll
                    for (int n = 0; n < 2; ++n)
                        acc[m][n] = __builtin_amdgcn_mfma_f32_16x16x32_bf16(af[m], bfr[n], acc[m][n], 0, 0, 0);
            }
            __syncthreads();
        }

        // ---- epilogue: masked exp sums ----
        // C/D layout: col = lane&15, row = (lane>>4)*4 + reg
        const int rowbase = brow + wm;
        float sqr[4][4]; int labr[4][4];
        #pragma unroll
        for (int m = 0; m < 4; ++m)
            #pragma unroll
            for (int r = 0; r < 4; ++r) {
                int row = rowbase + m * 16 + lhi * 4 + r;
                sqr[m][r] = sq[row];
                labr[m][r] = labels[row];
            }
        float sqc[2]; int labc[2];
        #pragma unroll
        for (int n = 0; n < 2; ++n) {
            int col = bcol + wn + n * 16 + llo;
            sqc[n] = sq[col];
            labc[n] = labels[col];
        }

        float wsum[4][4] = {};
        float csum[2] = {};
        #pragma unroll
        for (int m = 0; m < 4; ++m)
            #pragma unroll
            for (int n = 0; n < 2; ++n)
                #pragma unroll
                for (int r = 0; r < 4; ++r) {
                    float g = acc[m][n][r];
                    float d2 = fmaxf(fmaf(-2.f, g, sqr[m][r] + sqc[n]), 0.f);
                    float dist = __builtin_amdgcn_sqrtf(d2);
                    // exp(1-d) = e * exp(-d); the e is folded into reduce1
                    float w = (labr[m][r] != labc[n]) ? __expf(-dist) : 0.f;
                    wsum[m][r] += w;
                    csum[n] += w;
                }
        // row sums: reduce across 16 llo lanes
        #pragma unroll
        for (int m = 0; m < 4; ++m)
            #pragma unroll
            for (int r = 0; r < 4; ++r) {
                float s = wsum[m][r];
                #pragma unroll
                for (int off = 1; off < 16; off <<= 1) s += __shfl_xor(s, off, 64);
                if (llo == 0)
                    atomicAdd(&rowsum[wm + m * 16 + lhi * 4 + r], s);
            }
        // col sums: reduce across the 4 lhi groups
        if (!diag) {
            #pragma unroll
            for (int n = 0; n < 2; ++n) {
                float s = csum[n];
                s += __shfl_xor(s, 16, 64);
                s += __shfl_xor(s, 32, 64);
                if (lhi == 0)
                    atomicAdd(&colsum[wn + n * 16 + llo], s);
            }
        }
        __syncthreads();
        if (tid < 128) {
            partial1[(size_t)bj * N + brow + tid] = rowsum[tid];
            if (!diag)
                partial1[(size_t)bi * N + bcol + tid] = colsum[tid];
        }
        // next iteration: rowsum/colsum re-zeroed by the same threads that
        // just read them (program order), staging barrier orders vs atomics.
    }
}

// sum_exp[row] = e * sum over column-blocks of partial1[cb][row]
__global__ void reduce1_kernel(const float* __restrict__ partial1,
                               float* __restrict__ sum_exp, int N, int nCb) {
    int row = blockIdx.x * 256 + threadIdx.x;
    if (row >= N) return;
    float s = 0.f;
    for (int cb = 0; cb < nCb; ++cb) s += partial1[(size_t)cb * N + row];
    sum_exp[row] = s * 2.71828182845904523f;
}

// PASS 2: one block per label; within-label Gram + loss (ordered counting).
// Last block (ticket) reduces partial2/cnt2 -> out.
__global__ __launch_bounds__(256) void pass2_kernel(
    const unsigned short* __restrict__ ebf,
    const float* __restrict__ sq,
    const float* __restrict__ sum_exp,
    const int* __restrict__ idxbuf,
    const int* __restrict__ offsets,
    const int* __restrict__ counts,
    double* __restrict__ partial2,
    unsigned* __restrict__ cnt2,
    unsigned* __restrict__ ticket,
    float* __restrict__ out)
{
    __shared__ __align__(16) char a_tile[128 * 128];
    __shared__ __align__(16) char b_tile[128 * 128];
    __shared__ double bsum[4];
    __shared__ unsigned bcnt[4];
    __shared__ bool isLast;

    const int L = blockIdx.x;
    const int NL = gridDim.x;
    const int tid = threadIdx.x;
    const int lane = tid & 63, wid = tid >> 6;
    const int cnt = counts[L], offs = offsets[L];
    const int wm = (wid >> 1) * 64, wn = (wid & 1) * 64;
    const int lhi = lane >> 4, llo = lane & 15;
    const char* ebfB = (const char*)ebf;

    float lsum = 0.f; unsigned lcnt = 0;

    if (cnt > 1) {
        const int nSub = (cnt + 127) >> 7;
        for (int si = 0; si < nSub; ++si)
        for (int sj = si; sj < nSub; ++sj) {
            const int baseA = offs + si * 128, baseB = offs + sj * 128;
            const int cntA = min(128, cnt - si * 128);
            const int cntB = min(128, cnt - sj * 128);
            const float wgt = (si == sj) ? 1.f : 2.f;
            const unsigned wgtu = (si == sj) ? 1u : 2u;

            f32x4 acc[4][4];
            #pragma unroll
            for (int m = 0; m < 4; ++m)
                #pragma unroll
                for (int n = 0; n < 4; ++n)
                    acc[m][n] = (f32x4){0.f, 0.f, 0.f, 0.f};

            for (int c = 0; c < 2; ++c) {
                // stage 2048 slots (reg-staged gather; rows clamped, masked later)
                #pragma unroll
                for (int i2 = 0; i2 < 8; ++i2) {
                    int sl = tid + i2 * 256;
                    int tsel = sl >> 10;
                    int s = sl & 1023;
                    int r = s >> 3, j = s & 7;
                    int base = tsel ? baseB : baseA;
                    int cc = tsel ? cntB : cntA;
                    int gr = idxbuf[base + min(r, cc - 1)];
                    uint4 v = *(const uint4*)(ebfB + ((size_t)gr << 8) + c * 128 + (j << 4));
                    char* tp = tsel ? b_tile : a_tile;
                    *(uint4*)(tp + r * 128 + (((j << 4)) ^ ((r & 7) << 4))) = v;
                }
                __syncthreads();
                #pragma unroll
                for (int h = 0; h < 2; ++h) {
                    const int cb = h * 64 + lhi * 16;
                    bf16x8 af[4], bfr[4];
                    #pragma unroll
                    for (int m = 0; m < 4; ++m) {
                        int r = wm + m * 16 + llo;
                        af[m] = *(const bf16x8*)(a_tile + r * 128 + (cb ^ ((r & 7) << 4)));
                    }
                    #pragma unroll
                    for (int n = 0; n < 4; ++n) {
                        int r = wn + n * 16 + llo;
                        bfr[n] = *(const bf16x8*)(b_tile + r * 128 + (cb ^ ((r & 7) << 4)));
                    }
                    #pragma unroll
                    for (int m = 0; m < 4; ++m)
                        #pragma unroll
                        for (int n = 0; n < 4; ++n)
                            acc[m][n] = __builtin_amdgcn_mfma_f32_16x16x32_bf16(af[m], bfr[n], acc[m][n], 0, 0, 0);
                }
                __syncthreads();
            }

            // epilogue: positive-pair loss
            int giA[4][4]; float sqA[4][4], seA[4][4]; bool vA[4][4];
            #pragma unroll
            for (int m = 0; m < 4; ++m)
                #pragma unroll
                for (int r = 0; r < 4; ++r) {
                    int lr = wm + m * 16 + lhi * 4 + r;
                    vA[m][r] = lr < cntA;
                    int gi = idxbuf[baseA + min(lr, cntA - 1)];
                    giA[m][r] = gi;
                    sqA[m][r] = sq[gi];
                    seA[m][r] = sum_exp[gi];
                }
            int gjB[4]; float sqB[4], seB[4]; bool vB[4];
            #pragma unroll
            for (int n = 0; n < 4; ++n) {
                int lc = wn + n * 16 + llo;
                vB[n] = lc < cntB;
                int gj = idxbuf[baseB + min(lc, cntB - 1)];
                gjB[n] = gj;
                sqB[n] = sq[gj];
                seB[n] = sum_exp[gj];
            }
            #pragma unroll
            for (int m = 0; m < 4; ++m)
                #pragma unroll
                for (int n = 0; n < 4; ++n)
                    #pragma unroll
                    for (int r = 0; r < 4; ++r) {
                        float g = acc[m][n][r];
                        float d2 = fmaxf(fmaf(-2.f, g, sqA[m][r] + sqB[n]), 0.f);
                        float dist = __builtin_amdgcn_sqrtf(d2);
                        bool pos = vA[m][r] && vB[n] && (giA[m][r] != gjB[n]);
                        float Lv = __logf(seA[m][r] + seB[n]) + dist;
                        Lv = fmaxf(Lv, 0.f);
                        lsum += pos ? wgt * Lv * Lv : 0.f;
                        lcnt += pos ? wgtu : 0u;
                    }
        }
    }

    // block reduce
    #pragma unroll
    for (int off = 1; off < 64; off <<= 1) {
        lsum += __shfl_xor(lsum, off, 64);
        lcnt += __shfl_xor(lcnt, off, 64);
    }
    if (lane == 0) { bsum[wid] = (double)lsum; bcnt[wid] = lcnt; }
    __syncthreads();
    if (tid == 0) {
        partial2[L] = bsum[0] + bsum[1] + bsum[2] + bsum[3];
        cnt2[L] = bcnt[0] + bcnt[1] + bcnt[2] + bcnt[3];
        __threadfence();
        isLast = (atomicAdd(ticket, 1u) == (unsigned)(NL - 1));
    }
    __syncthreads();

    // last block: final reduce -> out  (out = ordered_sum / n_pos / 2)
    if (isLast) {
        __threadfence();   // acquire: see all blocks' partial2/cnt2
        double tt = (tid < NL) ? partial2[tid] : 0.0;
        unsigned c = (tid < NL) ? cnt2[tid] : 0u;
        #pragma unroll
        for (int off = 1; off < 64; off <<= 1) {
            tt += __shfl_xor(tt, off, 64);
            c  += __shfl_xor(c, off, 64);
        }
        if (lane == 0) { bsum[wid] = tt; bcnt[wid] = c; }
        __syncthreads();
        if (tid == 0) {
            double s = bsum[0] + bsum[1] + bsum[2] + bsum[3];
            unsigned cc = bcnt[0] + bcnt[1] + bcnt[2] + bcnt[3];
            if (cc == 0) cc = 1;
            out[0] = (float)(s / (double)cc * 0.5);
        }
    }
}

extern "C" void kernel_launch(void* const* d_in, const int* in_sizes, int n_in,
                              void* d_out, int out_size, void* d_ws, size_t ws_size,
                              hipStream_t stream) {
    const float* e = (const float*)d_in[0];
    const int* labels = (const int*)d_in[1];
    const int N = in_sizes[1];                 // 8192
    const int nCb = N / 128;                   // 64
    const int nT = nCb * (nCb + 1) / 2;        // 2080
    const int NL = 256;

    char* ws = (char*)d_ws;
    float*    sq       = (float*)ws;
    float*    sum_exp  = (float*)(ws + 4 * (size_t)N);
    unsigned short* ebf = (unsigned short*)(ws + 8 * (size_t)N);
    char*     p        = ws + 8 * (size_t)N + 256 * (size_t)N;
    float*    partial1 = (float*)p;            // nCb*N floats (2 MB)
    p += (size_t)nCb * N * 4;
    int*      counts   = (int*)p;      p += NL * 4;
    int*      offsets  = (int*)p;      p += NL * 4;
    unsigned* ticket   = (unsigned*)p; p += 64;           // own cache line
    p = (char*)(((size_t)p + 7) & ~(size_t)7);
    double*   partial2 = (double*)p;   p += NL * 8;
    unsigned* cnt2     = (unsigned*)p; p += NL * 4;
    int*      idxbuf   = (int*)p;

    prep_kernel<<<(N + 31) / 32, 256, 0, stream>>>(e, sq, (unsigned*)ebf, N);
    bucket_kernel<<<1, 1024, 0, stream>>>(labels, counts, offsets, idxbuf, ticket, N);
    pass1_kernel<<<1040, 512, 0, stream>>>(ebf, sq, labels, partial1, N, nCb, nT);
    reduce1_kernel<<<(N + 255) / 256, 256, 0, stream>>>(partial1, sum_exp, N, nCb);
    pass2_kernel<<<NL, 256, 0, stream>>>(ebf, sq, sum_exp, idxbuf, offsets, counts,
                                         partial2, cnt2, ticket, (float*)d_out);
}

// Round 8
// 110.796 us; speedup vs baseline: 1.0178x; 1.0178x over previous
//
#include <hip/hip_runtime.h>
#include <hip/hip_bf16.h>

// LiftedStructureLoss on MI355X (gfx950)
// N=8192, D=128 fp32 embeddings; int labels (0..99); scalar fp32 out.
//
// Structure:
//   prep:     sq[] + bf16 convert (fat blocks)
//   bucket:   single-block zero+hist+scan+scatter (labels -> idxbuf); zeroes ticket
//   pass1:    upper-triangle 128x128 tiles, LDS-FREE: MFMA fragments loaded
//             directly global->register (Gram fragments are contiguous row
//             chunks; data is L1/L2-resident). No main-loop barriers.
//   reduce1:  partial1 -> sum_exp[N]  (x e, folding the MARGIN=1 exp)
//   pass2:    per-label blocks, within-label Gram (~1% of pairs), loss+n_pos;
//             last block (ticket) reduces partials -> out

typedef __attribute__((ext_vector_type(8))) short bf16x8;
typedef __attribute__((ext_vector_type(4))) float f32x4;

__device__ __forceinline__ unsigned short f2bf(float f) {
    unsigned u = __float_as_uint(f);
    u += 0x7fffu + ((u >> 16) & 1u);   // round-to-nearest-even
    return (unsigned short)(u >> 16);
}

// 256 blocks x 256 thr; each wave handles 8 rows.
__global__ __launch_bounds__(256) void prep_kernel(
    const float* __restrict__ e, float* __restrict__ sq,
    unsigned* __restrict__ ebf, int N) {
    const int lane = threadIdx.x & 63, wid = threadIdx.x >> 6;
    const int rowbase = (blockIdx.x * 4 + wid) * 8;
    #pragma unroll
    for (int it = 0; it < 8; ++it) {
        int row = rowbase + it;
        if (row >= N) break;
        float2 v = ((const float2*)(e + (size_t)row * 128))[lane];
        float s = v.x * v.x + v.y * v.y;
        #pragma unroll
        for (int off = 1; off < 64; off <<= 1) s += __shfl_xor(s, off, 64);
        if (lane == 0) sq[row] = s;
        unsigned bits = (unsigned)f2bf(v.x) | ((unsigned)f2bf(v.y) << 16);
        ebf[(size_t)row * 64 + lane] = bits;
    }
}

// Single block: zero + histogram + exclusive scan + scatter; zeroes ticket.
__global__ __launch_bounds__(1024) void bucket_kernel(
    const int* __restrict__ labels,
    int* __restrict__ counts_out,    // [256]
    int* __restrict__ offsets_out,   // [256]
    int* __restrict__ idxbuf,        // [N]
    unsigned* __restrict__ ticket,
    int N)
{
    __shared__ int cnt[256];
    __shared__ int off[256];
    const int tid = threadIdx.x;
    if (tid == 0) *ticket = 0u;
    if (tid < 256) cnt[tid] = 0;
    __syncthreads();
    for (int i = tid; i < N; i += 1024)
        atomicAdd(&cnt[(unsigned)labels[i] & 255u], 1);
    __syncthreads();
    if (tid < 64) {
        int base = tid * 4;
        int c0 = cnt[base], c1 = cnt[base + 1], c2 = cnt[base + 2], c3 = cnt[base + 3];
        int s = c0 + c1 + c2 + c3;
        int v = s;
        #pragma unroll
        for (int d = 1; d < 64; d <<= 1) {
            int u = __shfl_up(v, d, 64);
            if (tid >= d) v += u;
        }
        int excl = v - s;
        off[base]     = excl;
        off[base + 1] = excl + c0;
        off[base + 2] = excl + c0 + c1;
        off[base + 3] = excl + c0 + c1 + c2;
    }
    __syncthreads();
    if (tid < 256) cnt[tid] = off[tid];   // reuse cnt as cursor
    __syncthreads();
    for (int i = tid; i < N; i += 1024) {
        int l = (unsigned)labels[i] & 255u;
        int p = atomicAdd(&cnt[l], 1);
        idxbuf[p] = i;
    }
    __syncthreads();
    if (tid < 256) {
        offsets_out[tid] = off[tid];
        counts_out[tid] = cnt[tid] - off[tid];
    }
}

// PASS 1: one 128x128 tile per block, 256 thr = 4 waves (2x2 of 64x64).
// LDS-free MFMA: fragments are 16B contiguous row chunks of ebf, loaded
// straight into registers. No barriers until the final combine.
__global__ __launch_bounds__(256) void pass1_kernel(
    const unsigned short* __restrict__ ebf,
    const float* __restrict__ sq,
    const int* __restrict__ labels,
    float* __restrict__ partial1,      // [nCb][N]
    int N, int nCb)
{
    __shared__ float rowsum[128];
    __shared__ float colsum[128];

    const int tid = threadIdx.x;
    const int lane = tid & 63, wid = tid >> 6;

    // decode linear tile id -> (bi, bj), bi <= bj
    const int t = blockIdx.x;
    int bi = (int)((2.f * nCb + 1.f - __builtin_amdgcn_sqrtf(
                   (2.f * nCb + 1.f) * (2.f * nCb + 1.f) - 8.f * t)) * 0.5f);
    if (bi < 0) bi = 0;
    if (bi > nCb - 1) bi = nCb - 1;
    while (bi + 1 <= nCb - 1 && (bi + 1) * (2 * nCb - bi) / 2 <= t) ++bi;
    while (bi > 0 && bi * (2 * nCb - bi + 1) / 2 > t) --bi;
    const int bj = bi + (t - bi * (2 * nCb - bi + 1) / 2);
    const bool diag = (bi == bj);
    const int brow = bi * 128, bcol = bj * 128;

    if (tid < 128) { rowsum[tid] = 0.f; colsum[tid] = 0.f; }
    __syncthreads();    // zeroing visible before any atomicAdd below

    const int wm = (wid >> 1) * 64, wn = (wid & 1) * 64;
    const int lhi = lane >> 4, llo = lane & 15;
    const char* ebfB = (const char*)ebf;

    f32x4 acc[4][4];
    #pragma unroll
    for (int m = 0; m < 4; ++m)
        #pragma unroll
        for (int n = 0; n < 4; ++n)
            acc[m][n] = (f32x4){0.f, 0.f, 0.f, 0.f};

    // A-fragment rows for this wave: brow+wm + m*16 + llo, byte col ks*64+lhi*16
    const char* aBase = ebfB + ((size_t)(brow + wm + llo) << 8) + lhi * 16;
    const char* bBase = ebfB + ((size_t)(bcol + wn + llo) << 8) + lhi * 16;

    #pragma unroll
    for (int ks = 0; ks < 4; ++ks) {
        bf16x8 af[4], bfr[4];
        #pragma unroll
        for (int m = 0; m < 4; ++m)
            af[m] = *(const bf16x8*)(aBase + ((size_t)(m * 16) << 8) + ks * 64);
        #pragma unroll
        for (int n = 0; n < 4; ++n)
            bfr[n] = *(const bf16x8*)(bBase + ((size_t)(n * 16) << 8) + ks * 64);
        #pragma unroll
        for (int m = 0; m < 4; ++m)
            #pragma unroll
            for (int n = 0; n < 4; ++n)
                acc[m][n] = __builtin_amdgcn_mfma_f32_16x16x32_bf16(af[m], bfr[n], acc[m][n], 0, 0, 0);
    }

    // ---- epilogue: masked exp sums ----
    // C/D layout: col = lane&15, row = (lane>>4)*4 + reg
    const int rowbase = brow + wm;
    float sqr[4][4]; int labr[4][4];
    #pragma unroll
    for (int m = 0; m < 4; ++m)
        #pragma unroll
        for (int r = 0; r < 4; ++r) {
            int row = rowbase + m * 16 + lhi * 4 + r;
            sqr[m][r] = sq[row];
            labr[m][r] = labels[row];
        }
    float sqc[4]; int labc[4];
    #pragma unroll
    for (int n = 0; n < 4; ++n) {
        int col = bcol + wn + n * 16 + llo;
        sqc[n] = sq[col];
        labc[n] = labels[col];
    }

    float wsum[4][4] = {};
    float csum[4] = {};
    #pragma unroll
    for (int m = 0; m < 4; ++m)
        #pragma unroll
        for (int n = 0; n < 4; ++n)
            #pragma unroll
            for (int r = 0; r < 4; ++r) {
                float g = acc[m][n][r];
                float d2 = fmaxf(fmaf(-2.f, g, sqr[m][r] + sqc[n]), 0.f);
                float dist = __builtin_amdgcn_sqrtf(d2);
                // exp(1-d) = e * exp(-d); the e is folded into reduce1
                float w = (labr[m][r] != labc[n]) ? __expf(-dist) : 0.f;
                wsum[m][r] += w;
                csum[n] += w;
            }
    // row sums: reduce across 16 llo lanes
    #pragma unroll
    for (int m = 0; m < 4; ++m)
        #pragma unroll
        for (int r = 0; r < 4; ++r) {
            float s = wsum[m][r];
            #pragma unroll
            for (int off = 1; off < 16; off <<= 1) s += __shfl_xor(s, off, 64);
            if (llo == 0)
                atomicAdd(&rowsum[wm + m * 16 + lhi * 4 + r], s);
        }
    // col sums: reduce across the 4 lhi groups
    if (!diag) {
        #pragma unroll
        for (int n = 0; n < 4; ++n) {
            float s = csum[n];
            s += __shfl_xor(s, 16, 64);
            s += __shfl_xor(s, 32, 64);
            if (lhi == 0)
                atomicAdd(&colsum[wn + n * 16 + llo], s);
        }
    }
    __syncthreads();
    if (tid < 128) {
        partial1[(size_t)bj * N + brow + tid] = rowsum[tid];
        if (!diag)
            partial1[(size_t)bi * N + bcol + tid] = colsum[tid];
    }
}

// sum_exp[row] = e * sum over column-blocks of partial1[cb][row]
__global__ void reduce1_kernel(const float* __restrict__ partial1,
                               float* __restrict__ sum_exp, int N, int nCb) {
    int row = blockIdx.x * 256 + threadIdx.x;
    if (row >= N) return;
    float s = 0.f;
    for (int cb = 0; cb < nCb; ++cb) s += partial1[(size_t)cb * N + row];
    sum_exp[row] = s * 2.71828182845904523f;
}

// PASS 2: one block per label; within-label Gram + loss (ordered counting).
// Last block (ticket) reduces partial2/cnt2 -> out.
__global__ __launch_bounds__(256) void pass2_kernel(
    const unsigned short* __restrict__ ebf,
    const float* __restrict__ sq,
    const float* __restrict__ sum_exp,
    const int* __restrict__ idxbuf,
    const int* __restrict__ offsets,
    const int* __restrict__ counts,
    double* __restrict__ partial2,
    unsigned* __restrict__ cnt2,
    unsigned* __restrict__ ticket,
    float* __restrict__ out)
{
    __shared__ __align__(16) char a_tile[128 * 128];
    __shared__ __align__(16) char b_tile[128 * 128];
    __shared__ double bsum[4];
    __shared__ unsigned bcnt[4];
    __shared__ bool isLast;

    const int L = blockIdx.x;
    const int NL = gridDim.x;
    const int tid = threadIdx.x;
    const int lane = tid & 63, wid = tid >> 6;
    const int cnt = counts[L], offs = offsets[L];
    const int wm = (wid >> 1) * 64, wn = (wid & 1) * 64;
    const int lhi = lane >> 4, llo = lane & 15;
    const char* ebfB = (const char*)ebf;

    float lsum = 0.f; unsigned lcnt = 0;

    if (cnt > 1) {
        const int nSub = (cnt + 127) >> 7;
        for (int si = 0; si < nSub; ++si)
        for (int sj = si; sj < nSub; ++sj) {
            const int baseA = offs + si * 128, baseB = offs + sj * 128;
            const int cntA = min(128, cnt - si * 128);
            const int cntB = min(128, cnt - sj * 128);
            const float wgt = (si == sj) ? 1.f : 2.f;
            const unsigned wgtu = (si == sj) ? 1u : 2u;

            f32x4 acc[4][4];
            #pragma unroll
            for (int m = 0; m < 4; ++m)
                #pragma unroll
                for (int n = 0; n < 4; ++n)
                    acc[m][n] = (f32x4){0.f, 0.f, 0.f, 0.f};

            for (int c = 0; c < 2; ++c) {
                // stage 2048 slots (reg-staged gather; rows clamped, masked later)
                #pragma unroll
                for (int i2 = 0; i2 < 8; ++i2) {
                    int sl = tid + i2 * 256;
                    int tsel = sl >> 10;
                    int s = sl & 1023;
                    int r = s >> 3, j = s & 7;
                    int base = tsel ? baseB : baseA;
                    int cc = tsel ? cntB : cntA;
                    int gr = idxbuf[base + min(r, cc - 1)];
                    uint4 v = *(const uint4*)(ebfB + ((size_t)gr << 8) + c * 128 + (j << 4));
                    char* tp = tsel ? b_tile : a_tile;
                    *(uint4*)(tp + r * 128 + (((j << 4)) ^ ((r & 7) << 4))) = v;
                }
                __syncthreads();
                #pragma unroll
                for (int h = 0; h < 2; ++h) {
                    const int cb = h * 64 + lhi * 16;
                    bf16x8 af[4], bfr[4];
                    #pragma unroll
                    for (int m = 0; m < 4; ++m) {
                        int r = wm + m * 16 + llo;
                        af[m] = *(const bf16x8*)(a_tile + r * 128 + (cb ^ ((r & 7) << 4)));
                    }
                    #pragma unroll
                    for (int n = 0; n < 4; ++n) {
                        int r = wn + n * 16 + llo;
                        bfr[n] = *(const bf16x8*)(b_tile + r * 128 + (cb ^ ((r & 7) << 4)));
                    }
                    #pragma unroll
                    for (int m = 0; m < 4; ++m)
                        #pragma unroll
                        for (int n = 0; n < 4; ++n)
                            acc[m][n] = __builtin_amdgcn_mfma_f32_16x16x32_bf16(af[m], bfr[n], acc[m][n], 0, 0, 0);
                }
                __syncthreads();
            }

            // epilogue: positive-pair loss
            int giA[4][4]; float sqA[4][4], seA[4][4]; bool vA[4][4];
            #pragma unroll
            for (int m = 0; m < 4; ++m)
                #pragma unroll
                for (int r = 0; r < 4; ++r) {
                    int lr = wm + m * 16 + lhi * 4 + r;
                    vA[m][r] = lr < cntA;
                    int gi = idxbuf[baseA + min(lr, cntA - 1)];
                    giA[m][r] = gi;
                    sqA[m][r] = sq[gi];
                    seA[m][r] = sum_exp[gi];
                }
            int gjB[4]; float sqB[4], seB[4]; bool vB[4];
            #pragma unroll
            for (int n = 0; n < 4; ++n) {
                int lc = wn + n * 16 + llo;
                vB[n] = lc < cntB;
                int gj = idxbuf[baseB + min(lc, cntB - 1)];
                gjB[n] = gj;
                sqB[n] = sq[gj];
                seB[n] = sum_exp[gj];
            }
            #pragma unroll
            for (int m = 0; m < 4; ++m)
                #pragma unroll
                for (int n = 0; n < 4; ++n)
                    #pragma unroll
                    for (int r = 0; r < 4; ++r) {
                        float g = acc[m][n][r];
                        float d2 = fmaxf(fmaf(-2.f, g, sqA[m][r] + sqB[n]), 0.f);
                        float dist = __builtin_amdgcn_sqrtf(d2);
                        bool pos = vA[m][r] && vB[n] && (giA[m][r] != gjB[n]);
                        float Lv = __logf(seA[m][r] + seB[n]) + dist;
                        Lv = fmaxf(Lv, 0.f);
                        lsum += pos ? wgt * Lv * Lv : 0.f;
                        lcnt += pos ? wgtu : 0u;
                    }
        }
    }

    // block reduce
    #pragma unroll
    for (int off = 1; off < 64; off <<= 1) {
        lsum += __shfl_xor(lsum, off, 64);
        lcnt += __shfl_xor(lcnt, off, 64);
    }
    if (lane == 0) { bsum[wid] = (double)lsum; bcnt[wid] = lcnt; }
    __syncthreads();
    if (tid == 0) {
        partial2[L] = bsum[0] + bsum[1] + bsum[2] + bsum[3];
        cnt2[L] = bcnt[0] + bcnt[1] + bcnt[2] + bcnt[3];
        __threadfence();
        isLast = (atomicAdd(ticket, 1u) == (unsigned)(NL - 1));
    }
    __syncthreads();

    // last block: final reduce -> out  (out = ordered_sum / n_pos / 2)
    if (isLast) {
        __threadfence();   // acquire: see all blocks' partial2/cnt2
        double tt = (tid < NL) ? partial2[tid] : 0.0;
        unsigned c = (tid < NL) ? cnt2[tid] : 0u;
        #pragma unroll
        for (int off = 1; off < 64; off <<= 1) {
            tt += __shfl_xor(tt, off, 64);
            c  += __shfl_xor(c, off, 64);
        }
        if (lane == 0) { bsum[wid] = tt; bcnt[wid] = c; }
        __syncthreads();
        if (tid == 0) {
            double s = bsum[0] + bsum[1] + bsum[2] + bsum[3];
            unsigned cc = bcnt[0] + bcnt[1] + bcnt[2] + bcnt[3];
            if (cc == 0) cc = 1;
            out[0] = (float)(s / (double)cc * 0.5);
        }
    }
}

extern "C" void kernel_launch(void* const* d_in, const int* in_sizes, int n_in,
                              void* d_out, int out_size, void* d_ws, size_t ws_size,
                              hipStream_t stream) {
    const float* e = (const float*)d_in[0];
    const int* labels = (const int*)d_in[1];
    const int N = in_sizes[1];                 // 8192
    const int nCb = N / 128;                   // 64
    const int nT = nCb * (nCb + 1) / 2;        // 2080
    const int NL = 256;

    char* ws = (char*)d_ws;
    float*    sq       = (float*)ws;
    float*    sum_exp  = (float*)(ws + 4 * (size_t)N);
    unsigned short* ebf = (unsigned short*)(ws + 8 * (size_t)N);
    char*     p        = ws + 8 * (size_t)N + 256 * (size_t)N;
    float*    partial1 = (float*)p;            // nCb*N floats (2 MB)
    p += (size_t)nCb * N * 4;
    int*      counts   = (int*)p;      p += NL * 4;
    int*      offsets  = (int*)p;      p += NL * 4;
    unsigned* ticket   = (unsigned*)p; p += 64;           // own cache line
    p = (char*)(((size_t)p + 7) & ~(size_t)7);
    double*   partial2 = (double*)p;   p += NL * 8;
    unsigned* cnt2     = (unsigned*)p; p += NL * 4;
    int*      idxbuf   = (int*)p;

    prep_kernel<<<(N + 31) / 32, 256, 0, stream>>>(e, sq, (unsigned*)ebf, N);
    bucket_kernel<<<1, 1024, 0, stream>>>(labels, counts, offsets, idxbuf, ticket, N);
    pass1_kernel<<<nT, 256, 0, stream>>>(ebf, sq, labels, partial1, N, nCb);
    reduce1_kernel<<<(N + 255) / 256, 256, 0, stream>>>(partial1, sum_exp, N, nCb);
    pass2_kernel<<<NL, 256, 0, stream>>>(ebf, sq, sum_exp, idxbuf, offsets, counts,
                                         partial2, cnt2, ticket, (float*)d_out);
}

// Round 9
// 72.634 us; speedup vs baseline: 1.5526x; 1.5254x over previous
//
#include <hip/hip_runtime.h>
#include <hip/hip_bf16.h>

// LiftedStructureLoss on MI355X (gfx950)
// N=8192, D=128 fp32 embeddings; int labels (0..99); scalar fp32 out.
//
// 3 launches:
//   setup:  blocks 0..255 = prep (sq, bf16 convert, zero sum_exp slice);
//           block 256     = bucket (zero+hist+scan+scatter, zero ticket)
//   pass1:  upper-triangle 128x128 tiles, 512 thr, global_load_lds staging;
//           row+col sums of exp(-d) over negatives -> unsafeAtomicAdd(sum_exp)
//   pass2:  per-label within-label Gram (~1% of pairs) -> loss + n_pos;
//           ticket: last block reduces partials -> out
//
// exp(1-d) = e * exp(-d): the e is folded into pass2's sum_exp reads.

typedef __attribute__((ext_vector_type(8))) short bf16x8;
typedef __attribute__((ext_vector_type(4))) float f32x4;

__device__ __forceinline__ unsigned short f2bf(float f) {
    unsigned u = __float_as_uint(f);
    u += 0x7fffu + ((u >> 16) & 1u);   // round-to-nearest-even
    return (unsigned short)(u >> 16);
}

// Blocks 0..nPrep-1: prep 32 rows each (4 waves x 8 rows) + zero sum_exp.
// Block nPrep: bucket labels (256 threads).
__global__ __launch_bounds__(256) void setup_kernel(
    const float* __restrict__ e, const int* __restrict__ labels,
    float* __restrict__ sq, unsigned* __restrict__ ebf,
    float* __restrict__ sum_exp,
    int* __restrict__ counts_out, int* __restrict__ offsets_out,
    int* __restrict__ idxbuf, unsigned* __restrict__ ticket, int N)
{
    const int tid = threadIdx.x;
    if ((int)blockIdx.x < (int)gridDim.x - 1) {
        // ---- prep path ----
        const int lane = tid & 63, wid = tid >> 6;
        if (tid < 32) sum_exp[blockIdx.x * 32 + tid] = 0.f;
        const int rowbase = (blockIdx.x * 4 + wid) * 8;
        #pragma unroll
        for (int it = 0; it < 8; ++it) {
            int row = rowbase + it;
            if (row >= N) break;
            float2 v = ((const float2*)(e + (size_t)row * 128))[lane];
            float s = v.x * v.x + v.y * v.y;
            #pragma unroll
            for (int off = 1; off < 64; off <<= 1) s += __shfl_xor(s, off, 64);
            if (lane == 0) sq[row] = s;
            unsigned bits = (unsigned)f2bf(v.x) | ((unsigned)f2bf(v.y) << 16);
            ebf[(size_t)row * 64 + lane] = bits;
        }
    } else {
        // ---- bucket path (256 threads) ----
        __shared__ int cnt[256];
        __shared__ int off[256];
        if (tid == 0) *ticket = 0u;
        cnt[tid] = 0;
        __syncthreads();
        for (int i = tid; i < N; i += 256)
            atomicAdd(&cnt[(unsigned)labels[i] & 255u], 1);
        __syncthreads();
        if (tid < 64) {
            int base = tid * 4;
            int c0 = cnt[base], c1 = cnt[base+1], c2 = cnt[base+2], c3 = cnt[base+3];
            int s = c0 + c1 + c2 + c3;
            int v = s;
            #pragma unroll
            for (int d = 1; d < 64; d <<= 1) {
                int u = __shfl_up(v, d, 64);
                if (tid >= d) v += u;
            }
            int excl = v - s;
            off[base]     = excl;
            off[base + 1] = excl + c0;
            off[base + 2] = excl + c0 + c1;
            off[base + 3] = excl + c0 + c1 + c2;
        }
        __syncthreads();
        counts_out[tid]  = cnt[tid];
        offsets_out[tid] = off[tid];
        cnt[tid] = off[tid];               // reuse as cursor
        __syncthreads();
        for (int i = tid; i < N; i += 256) {
            int l = (unsigned)labels[i] & 255u;
            int p = atomicAdd(&cnt[l], 1);
            idxbuf[p] = i;
        }
    }
}

// PASS 1: one 128x128 upper-triangle tile per block, 512 thr = 8 waves of
// 64x32. K=128 in 2 chunks of 64, async global_load_lds staging (linear LDS
// dest + inverse-swizzled global src), swizzled ds_read.
__global__ __launch_bounds__(512) void pass1_kernel(
    const unsigned short* __restrict__ ebf,
    const float* __restrict__ sq,
    const int* __restrict__ labels,
    float* __restrict__ sum_exp,       // accumulated via fp32 atomics
    int N, int nCb)
{
    __shared__ __align__(16) char a_tile[128 * 128];
    __shared__ __align__(16) char b_tile[128 * 128];
    __shared__ float rowsum[128];
    __shared__ float colsum[128];

    const int tid = threadIdx.x;
    const int lane = tid & 63, wid = tid >> 6;

    // decode linear tile id -> (bi, bj), bi <= bj
    const int t = blockIdx.x;
    int bi = (int)((2.f * nCb + 1.f - __builtin_amdgcn_sqrtf(
                   (2.f * nCb + 1.f) * (2.f * nCb + 1.f) - 8.f * t)) * 0.5f);
    if (bi < 0) bi = 0;
    if (bi > nCb - 1) bi = nCb - 1;
    while (bi + 1 <= nCb - 1 && (bi + 1) * (2 * nCb - bi) / 2 <= t) ++bi;
    while (bi > 0 && bi * (2 * nCb - bi + 1) / 2 > t) --bi;
    const int bj = bi + (t - bi * (2 * nCb - bi + 1) / 2);
    const bool diag = (bi == bj);
    const int brow = bi * 128, bcol = bj * 128;

    if (tid < 128) { rowsum[tid] = 0.f; colsum[tid] = 0.f; }

    const int wm = (wid >> 2) * 64, wn = (wid & 3) * 32;
    const int lhi = lane >> 4, llo = lane & 15;
    const char* ebfB = (const char*)ebf;

    f32x4 acc[4][2];
    #pragma unroll
    for (int m = 0; m < 4; ++m)
        #pragma unroll
        for (int n = 0; n < 2; ++n)
            acc[m][n] = (f32x4){0.f, 0.f, 0.f, 0.f};

    #pragma unroll
    for (int c = 0; c < 2; ++c) {
        // async stage: 2048 16B slots, wave wid covers [wid*256, +256)
        #pragma unroll
        for (int k = 0; k < 4; ++k) {
            int s = wid * 256 + k * 64;          // wave-uniform slot base
            int tsel = s >> 10;                  // 0: a_tile, 1: b_tile
            int ls = s & 1023;
            int sl = ls + lane;                  // per-lane slot within tile
            int r = sl >> 3, j = sl & 7;
            int grow = (tsel ? bcol : brow) + r;
            const void* g = ebfB + ((size_t)grow << 8) + c * 128 + ((j ^ (r & 7)) << 4);
            char* l = (tsel ? b_tile : a_tile) + ls * 16;   // wave-uniform
            __builtin_amdgcn_global_load_lds(
                (const __attribute__((address_space(1))) unsigned*)g,
                (__attribute__((address_space(3))) unsigned*)l, 16, 0, 0);
        }
        __syncthreads();   // drains vmcnt before ds_read

        #pragma unroll
        for (int h = 0; h < 2; ++h) {
            const int cb = h * 64 + lhi * 16;
            bf16x8 af[4], bfr[2];
            #pragma unroll
            for (int m = 0; m < 4; ++m) {
                int r = wm + m * 16 + llo;
                af[m] = *(const bf16x8*)(a_tile + r * 128 + (cb ^ ((r & 7) << 4)));
            }
            #pragma unroll
            for (int n = 0; n < 2; ++n) {
                int r = wn + n * 16 + llo;
                bfr[n] = *(const bf16x8*)(b_tile + r * 128 + (cb ^ ((r & 7) << 4)));
            }
            #pragma unroll
            for (int m = 0; m < 4; ++m)
                #pragma unroll
                for (int n = 0; n < 2; ++n)
                    acc[m][n] = __builtin_amdgcn_mfma_f32_16x16x32_bf16(af[m], bfr[n], acc[m][n], 0, 0, 0);
        }
        __syncthreads();
    }

    // ---- epilogue: masked exp sums ----
    // C/D layout: col = lane&15, row = (lane>>4)*4 + reg
    const int rowbase = brow + wm;
    float sqr[4][4]; int labr[4][4];
    #pragma unroll
    for (int m = 0; m < 4; ++m)
        #pragma unroll
        for (int r = 0; r < 4; ++r) {
            int row = rowbase + m * 16 + lhi * 4 + r;
            sqr[m][r] = sq[row];
            labr[m][r] = labels[row];
        }
    float sqc[2]; int labc[2];
    #pragma unroll
    for (int n = 0; n < 2; ++n) {
        int col = bcol + wn + n * 16 + llo;
        sqc[n] = sq[col];
        labc[n] = labels[col];
    }

    float wsum[4][4] = {};
    float csum[2] = {};
    #pragma unroll
    for (int m = 0; m < 4; ++m)
        #pragma unroll
        for (int n = 0; n < 2; ++n)
            #pragma unroll
            for (int r = 0; r < 4; ++r) {
                float g = acc[m][n][r];
                float d2 = fmaxf(fmaf(-2.f, g, sqr[m][r] + sqc[n]), 0.f);
                float dist = __builtin_amdgcn_sqrtf(d2);
                float w = (labr[m][r] != labc[n]) ? __expf(-dist) : 0.f;
                wsum[m][r] += w;
                csum[n] += w;
            }
    // row sums: reduce across 16 llo lanes
    #pragma unroll
    for (int m = 0; m < 4; ++m)
        #pragma unroll
        for (int r = 0; r < 4; ++r) {
            float s = wsum[m][r];
            #pragma unroll
            for (int off = 1; off < 16; off <<= 1) s += __shfl_xor(s, off, 64);
            if (llo == 0)
                atomicAdd(&rowsum[wm + m * 16 + lhi * 4 + r], s);
        }
    // col sums: reduce across the 4 lhi groups
    if (!diag) {
        #pragma unroll
        for (int n = 0; n < 2; ++n) {
            float s = csum[n];
            s += __shfl_xor(s, 16, 64);
            s += __shfl_xor(s, 32, 64);
            if (lhi == 0)
                atomicAdd(&colsum[wn + n * 16 + llo], s);
        }
    }
    __syncthreads();
    if (tid < 128) {
        unsafeAtomicAdd(&sum_exp[brow + tid], rowsum[tid]);
        if (!diag)
            unsafeAtomicAdd(&sum_exp[bcol + tid], colsum[tid]);
    }
}

// PASS 2: one block per label; within-label Gram + loss (ordered counting).
// Last block (ticket) reduces partial2/cnt2 -> out.
__global__ __launch_bounds__(256) void pass2_kernel(
    const unsigned short* __restrict__ ebf,
    const float* __restrict__ sq,
    const float* __restrict__ sum_exp,
    const int* __restrict__ idxbuf,
    const int* __restrict__ offsets,
    const int* __restrict__ counts,
    double* __restrict__ partial2,
    unsigned* __restrict__ cnt2,
    unsigned* __restrict__ ticket,
    float* __restrict__ out)
{
    __shared__ __align__(16) char a_tile[128 * 128];
    __shared__ __align__(16) char b_tile[128 * 128];
    __shared__ double bsum[4];
    __shared__ unsigned bcnt[4];
    __shared__ bool isLast;

    const int L = blockIdx.x;
    const int NL = gridDim.x;
    const int tid = threadIdx.x;
    const int lane = tid & 63, wid = tid >> 6;
    const int cnt = counts[L], offs = offsets[L];
    const int wm = (wid >> 1) * 64, wn = (wid & 1) * 64;
    const int lhi = lane >> 4, llo = lane & 15;
    const char* ebfB = (const char*)ebf;
    const float E1 = 2.71828182845904523f;

    float lsum = 0.f; unsigned lcnt = 0;

    if (cnt > 1) {
        const int nSub = (cnt + 127) >> 7;
        for (int si = 0; si < nSub; ++si)
        for (int sj = si; sj < nSub; ++sj) {
            const int baseA = offs + si * 128, baseB = offs + sj * 128;
            const int cntA = min(128, cnt - si * 128);
            const int cntB = min(128, cnt - sj * 128);
            const float wgt = (si == sj) ? 1.f : 2.f;
            const unsigned wgtu = (si == sj) ? 1u : 2u;

            f32x4 acc[4][4];
            #pragma unroll
            for (int m = 0; m < 4; ++m)
                #pragma unroll
                for (int n = 0; n < 4; ++n)
                    acc[m][n] = (f32x4){0.f, 0.f, 0.f, 0.f};

            for (int c = 0; c < 2; ++c) {
                // stage 2048 slots (reg-staged gather; rows clamped, masked later)
                #pragma unroll
                for (int i2 = 0; i2 < 8; ++i2) {
                    int sl = tid + i2 * 256;
                    int tsel = sl >> 10;
                    int s = sl & 1023;
                    int r = s >> 3, j = s & 7;
                    int base = tsel ? baseB : baseA;
                    int cc = tsel ? cntB : cntA;
                    int gr = idxbuf[base + min(r, cc - 1)];
                    uint4 v = *(const uint4*)(ebfB + ((size_t)gr << 8) + c * 128 + (j << 4));
                    char* tp = tsel ? b_tile : a_tile;
                    *(uint4*)(tp + r * 128 + (((j << 4)) ^ ((r & 7) << 4))) = v;
                }
                __syncthreads();
                #pragma unroll
                for (int h = 0; h < 2; ++h) {
                    const int cb = h * 64 + lhi * 16;
                    bf16x8 af[4], bfr[4];
                    #pragma unroll
                    for (int m = 0; m < 4; ++m) {
                        int r = wm + m * 16 + llo;
                        af[m] = *(const bf16x8*)(a_tile + r * 128 + (cb ^ ((r & 7) << 4)));
                    }
                    #pragma unroll
                    for (int n = 0; n < 4; ++n) {
                        int r = wn + n * 16 + llo;
                        bfr[n] = *(const bf16x8*)(b_tile + r * 128 + (cb ^ ((r & 7) << 4)));
                    }
                    #pragma unroll
                    for (int m = 0; m < 4; ++m)
                        #pragma unroll
                        for (int n = 0; n < 4; ++n)
                            acc[m][n] = __builtin_amdgcn_mfma_f32_16x16x32_bf16(af[m], bfr[n], acc[m][n], 0, 0, 0);
                }
                __syncthreads();
            }

            // epilogue: positive-pair loss
            int giA[4][4]; float sqA[4][4], seA[4][4]; bool vA[4][4];
            #pragma unroll
            for (int m = 0; m < 4; ++m)
                #pragma unroll
                for (int r = 0; r < 4; ++r) {
                    int lr = wm + m * 16 + lhi * 4 + r;
                    vA[m][r] = lr < cntA;
                    int gi = idxbuf[baseA + min(lr, cntA - 1)];
                    giA[m][r] = gi;
                    sqA[m][r] = sq[gi];
                    seA[m][r] = sum_exp[gi] * E1;
                }
            int gjB[4]; float sqB[4], seB[4]; bool vB[4];
            #pragma unroll
            for (int n = 0; n < 4; ++n) {
                int lc = wn + n * 16 + llo;
                vB[n] = lc < cntB;
                int gj = idxbuf[baseB + min(lc, cntB - 1)];
                gjB[n] = gj;
                sqB[n] = sq[gj];
                seB[n] = sum_exp[gj] * E1;
            }
            #pragma unroll
            for (int m = 0; m < 4; ++m)
                #pragma unroll
                for (int n = 0; n < 4; ++n)
                    #pragma unroll
                    for (int r = 0; r < 4; ++r) {
                        float g = acc[m][n][r];
                        float d2 = fmaxf(fmaf(-2.f, g, sqA[m][r] + sqB[n]), 0.f);
                        float dist = __builtin_amdgcn_sqrtf(d2);
                        bool pos = vA[m][r] && vB[n] && (giA[m][r] != gjB[n]);
                        float Lv = __logf(seA[m][r] + seB[n]) + dist;
                        Lv = fmaxf(Lv, 0.f);
                        lsum += pos ? wgt * Lv * Lv : 0.f;
                        lcnt += pos ? wgtu : 0u;
                    }
        }
    }

    // block reduce
    #pragma unroll
    for (int off = 1; off < 64; off <<= 1) {
        lsum += __shfl_xor(lsum, off, 64);
        lcnt += __shfl_xor(lcnt, off, 64);
    }
    if (lane == 0) { bsum[wid] = (double)lsum; bcnt[wid] = lcnt; }
    __syncthreads();
    if (tid == 0) {
        partial2[L] = bsum[0] + bsum[1] + bsum[2] + bsum[3];
        cnt2[L] = bcnt[0] + bcnt[1] + bcnt[2] + bcnt[3];
        __threadfence();
        isLast = (atomicAdd(ticket, 1u) == (unsigned)(NL - 1));
    }
    __syncthreads();

    // last block: final reduce -> out  (out = ordered_sum / n_pos / 2)
    if (isLast) {
        __threadfence();   // acquire: see all blocks' partial2/cnt2
        double tt = (tid < NL) ? partial2[tid] : 0.0;
        unsigned c = (tid < NL) ? cnt2[tid] : 0u;
        #pragma unroll
        for (int off = 1; off < 64; off <<= 1) {
            tt += __shfl_xor(tt, off, 64);
            c  += __shfl_xor(c, off, 64);
        }
        if (lane == 0) { bsum[wid] = tt; bcnt[wid] = c; }
        __syncthreads();
        if (tid == 0) {
            double s = bsum[0] + bsum[1] + bsum[2] + bsum[3];
            unsigned cc = bcnt[0] + bcnt[1] + bcnt[2] + bcnt[3];
            if (cc == 0) cc = 1;
            out[0] = (float)(s / (double)cc * 0.5);
        }
    }
}

extern "C" void kernel_launch(void* const* d_in, const int* in_sizes, int n_in,
                              void* d_out, int out_size, void* d_ws, size_t ws_size,
                              hipStream_t stream) {
    const float* e = (const float*)d_in[0];
    const int* labels = (const int*)d_in[1];
    const int N = in_sizes[1];                 // 8192
    const int nCb = N / 128;                   // 64
    const int nT = nCb * (nCb + 1) / 2;        // 2080
    const int NL = 256;
    const int nPrep = N / 32;                  // 256

    char* ws = (char*)d_ws;
    float*    sq       = (float*)ws;
    float*    sum_exp  = (float*)(ws + 4 * (size_t)N);
    unsigned short* ebf = (unsigned short*)(ws + 8 * (size_t)N);
    char*     p        = ws + 8 * (size_t)N + 256 * (size_t)N;
    int*      counts   = (int*)p;      p += NL * 4;
    int*      offsets  = (int*)p;      p += NL * 4;
    unsigned* ticket   = (unsigned*)p; p += 64;           // own cache line
    p = (char*)(((size_t)p + 7) & ~(size_t)7);
    double*   partial2 = (double*)p;   p += NL * 8;
    unsigned* cnt2     = (unsigned*)p; p += NL * 4;
    int*      idxbuf   = (int*)p;

    setup_kernel<<<nPrep + 1, 256, 0, stream>>>(e, labels, sq, (unsigned*)ebf,
                                                sum_exp, counts, offsets,
                                                idxbuf, ticket, N);
    pass1_kernel<<<nT, 512, 0, stream>>>(ebf, sq, labels, sum_exp, N, nCb);
    pass2_kernel<<<NL, 256, 0, stream>>>(ebf, sq, sum_exp, idxbuf, offsets, counts,
                                         partial2, cnt2, ticket, (float*)d_out);
}